// Round 1
// baseline (383.795 us; speedup 1.0000x reference)
//
#include <hip/hip_runtime.h>

#define D_FEAT 128

// ---------------- CSR build ----------------

__global__ void hist_kernel(const int* __restrict__ ei, int E,
                            int* __restrict__ deg, int* __restrict__ pos) {
    int e = blockIdx.x * blockDim.x + threadIdx.x;
    if (e < E) {
        int d = ei[e];                      // dst = edge_index[0]
        pos[e] = atomicAdd(&deg[d], 1);
    }
}

// per-block exclusive scan of deg -> rowstart (local), block sums -> bsum.
// Also computes norm[i] = rsqrt(1 + deg[i]).
__global__ void scan_block(const int* __restrict__ deg, int N,
                           int* __restrict__ rowstart, int* __restrict__ bsum,
                           float* __restrict__ norm) {
    __shared__ int s[256];
    int t = threadIdx.x;
    int i = blockIdx.x * 256 + t;
    int v = (i < N) ? deg[i] : 0;
    if (i < N) norm[i] = rsqrtf(1.0f + (float)v);
    s[t] = v;
    __syncthreads();
    for (int o = 1; o < 256; o <<= 1) {
        int x = (t >= o) ? s[t - o] : 0;
        __syncthreads();
        s[t] += x;
        __syncthreads();
    }
    if (i < N) rowstart[i] = s[t] - v;      // exclusive within block
    if (t == 255) bsum[blockIdx.x] = s[255];
}

// single-block exclusive scan of block sums (nb <= 512)
__global__ void scan_top(const int* __restrict__ bsum, int* __restrict__ boff, int nb) {
    __shared__ int s[512];
    int t = threadIdx.x;
    int v = (t < nb) ? bsum[t] : 0;
    s[t] = v;
    __syncthreads();
    for (int o = 1; o < 512; o <<= 1) {
        int x = (t >= o) ? s[t - o] : 0;
        __syncthreads();
        s[t] += x;
        __syncthreads();
    }
    if (t < nb) boff[t] = s[t] - v;
}

__global__ void scan_add(int* __restrict__ rowstart, const int* __restrict__ boff,
                         int N, int E) {
    int i = blockIdx.x * blockDim.x + threadIdx.x;
    if (i < N) rowstart[i] += boff[i >> 8];
    if (i == 0) rowstart[N] = E;
}

__global__ void scatter_kernel(const int* __restrict__ ei, int E,
                               const int* __restrict__ rowstart,
                               const int* __restrict__ pos,
                               int* __restrict__ esrc) {
    int e = blockIdx.x * blockDim.x + threadIdx.x;
    if (e < E) {
        int d = ei[e];          // dst
        int s = ei[E + e];      // src
        esrc[rowstart[d] + pos[e]] = s;
    }
}

// ---------------- fused conv ----------------
// out[i][d] = norm[i] * ( norm[i]*h[i][d] + sum_j norm[j]*h[j][d] ) [+ ori[i][d]]
template <int ADD_ORI>
__global__ __launch_bounds__(128) void conv_kernel(const float* __restrict__ h,
                                                   const float* __restrict__ ori,
                                                   float* __restrict__ out,
                                                   const float* __restrict__ norm,
                                                   const int* __restrict__ rowstart,
                                                   const int* __restrict__ esrc) {
    __shared__ int nbr[128];
    __shared__ float nrm[128];
    int i = blockIdx.x;
    int t = threadIdx.x;
    int r0 = rowstart[i], r1 = rowstart[i + 1];
    float ni = norm[i];
    long base = (long)i * D_FEAT;
    float acc = ni * h[base + t];           // self term (h' = norm*h)
    for (int b0 = r0; b0 < r1; b0 += 128) {
        int k = b0 + t;
        if (k < r1) {
            int j = esrc[k];
            nbr[t] = j;
            nrm[t] = norm[j];
        }
        __syncthreads();
        int cnt = min(128, r1 - b0);
        for (int q = 0; q < cnt; q++) {
            acc += nrm[q] * h[(long)nbr[q] * D_FEAT + t];
        }
        __syncthreads();
    }
    float o = ni * acc;
    if (ADD_ORI) o += ori[base + t];
    out[base + t] = o;
}

// ---------------- fused residual + affine-free LayerNorm (in-place) ----------------
// xbuf[i] = LN(xbuf[i] + ori[i]); one wave (64 lanes) per row, 2 feats/lane
__global__ __launch_bounds__(256) void add_ln_kernel(float* __restrict__ xbuf,
                                                     const float* __restrict__ ori,
                                                     int N) {
    int w = threadIdx.x >> 6;
    int lane = threadIdx.x & 63;
    int i = blockIdx.x * 4 + w;
    if (i >= N) return;
    long base = (long)i * D_FEAT;
    float2 a = ((const float2*)(xbuf + base))[lane];
    float2 b = ((const float2*)(ori + base))[lane];
    float v0 = a.x + b.x, v1 = a.y + b.y;
    float sum = v0 + v1;
    #pragma unroll
    for (int m = 1; m < 64; m <<= 1) sum += __shfl_xor(sum, m);
    float mean = sum * (1.0f / 128.0f);
    float d0 = v0 - mean, d1 = v1 - mean;
    float vs = d0 * d0 + d1 * d1;
    #pragma unroll
    for (int m = 1; m < 64; m <<= 1) vs += __shfl_xor(vs, m);
    float rs = rsqrtf(vs * (1.0f / 128.0f) + 1e-5f);
    float2 o;
    o.x = d0 * rs;
    o.y = d1 * rs;
    ((float2*)(xbuf + base))[lane] = o;
}

// ---------------- launch ----------------

extern "C" void kernel_launch(void* const* d_in, const int* in_sizes, int n_in,
                              void* d_out, int out_size, void* d_ws, size_t ws_size,
                              hipStream_t stream) {
    const float* x = (const float*)d_in[0];
    const int* ei = (const int*)d_in[1];
    int N = in_sizes[0] / D_FEAT;
    int E = in_sizes[1] / 2;
    float* out = (float*)d_out;

    char* ws = (char*)d_ws;
    size_t off = 0;
    auto alloc = [&](size_t bytes) -> void* {
        size_t cur = (off + 511) & ~(size_t)511;
        off = cur + bytes;
        return (void*)(ws + cur);
    };
    int* deg      = (int*)alloc((size_t)N * 4);
    int* rowstart = (int*)alloc((size_t)(N + 1) * 4);
    int* pos      = (int*)alloc((size_t)E * 4);
    int* esrc     = (int*)alloc((size_t)E * 4);
    float* norm   = (float*)alloc((size_t)N * 4);
    float* xbuf   = (float*)alloc((size_t)N * D_FEAT * 4);
    int* bsum     = (int*)alloc(1024 * 4);
    int* boff     = (int*)alloc(1024 * 4);
    (void)ws_size; (void)n_in; (void)out_size;

    hipMemsetAsync(deg, 0, (size_t)N * 4, stream);

    int eb = (E + 255) / 256;
    hist_kernel<<<eb, 256, 0, stream>>>(ei, E, deg, pos);

    int nb = (N + 255) / 256;                 // 391 for N=100000, <=512
    scan_block<<<nb, 256, 0, stream>>>(deg, N, rowstart, bsum, norm);
    scan_top<<<1, 512, 0, stream>>>(bsum, boff, nb);
    scan_add<<<nb, 256, 0, stream>>>(rowstart, boff, N, E);
    scatter_kernel<<<eb, 256, 0, stream>>>(ei, E, rowstart, pos, esrc);

    // layer 0: x1 = conv(x)
    conv_kernel<0><<<N, 128, 0, stream>>>(x, nullptr, xbuf, norm, rowstart, esrc);
    // layer 1 pre: x2 = LN(x1 + ori)   (in place)
    add_ln_kernel<<<(N + 3) / 4, 256, 0, stream>>>(xbuf, x, N);
    // layer 1: out = conv(x2) + ori
    conv_kernel<1><<<N, 128, 0, stream>>>(xbuf, x, out, norm, rowstart, esrc);
}

// Round 3
// 314.725 us; speedup vs baseline: 1.2195x; 1.2195x over previous
//
#include <hip/hip_runtime.h>

#define D_FEAT 128

// ---- bf16 as raw ushort: explicit round-to-nearest-even pack, shift unpack ----
__device__ __forceinline__ unsigned short f32_to_bf16(float f) {
    unsigned int u = __float_as_uint(f);
    u += 0x7fffu + ((u >> 16) & 1u);        // RNE
    return (unsigned short)(u >> 16);
}
__device__ __forceinline__ float bf16_to_f32(unsigned short h) {
    return __uint_as_float((unsigned int)h << 16);
}

// ---------------- CSR build ----------------

__global__ void hist_kernel(const int* __restrict__ ei, int E,
                            int* __restrict__ deg, int* __restrict__ pos) {
    int e = blockIdx.x * blockDim.x + threadIdx.x;
    if (e < E) {
        int d = ei[e];                      // dst = edge_index[0]
        pos[e] = atomicAdd(&deg[d], 1);
    }
}

// per-block exclusive scan of deg -> rowstart (local), block sums -> bsum.
// Also computes norm[i] = rsqrt(1 + deg[i]).
__global__ void scan_block(const int* __restrict__ deg, int N,
                           int* __restrict__ rowstart, int* __restrict__ bsum,
                           float* __restrict__ norm) {
    __shared__ int s[256];
    int t = threadIdx.x;
    int i = blockIdx.x * 256 + t;
    int v = (i < N) ? deg[i] : 0;
    if (i < N) norm[i] = rsqrtf(1.0f + (float)v);
    s[t] = v;
    __syncthreads();
    for (int o = 1; o < 256; o <<= 1) {
        int x = (t >= o) ? s[t - o] : 0;
        __syncthreads();
        s[t] += x;
        __syncthreads();
    }
    if (i < N) rowstart[i] = s[t] - v;      // exclusive within block
    if (t == 255) bsum[blockIdx.x] = s[255];
}

// single-block exclusive scan of block sums (nb <= 512)
__global__ void scan_top(const int* __restrict__ bsum, int* __restrict__ boff, int nb) {
    __shared__ int s[512];
    int t = threadIdx.x;
    int v = (t < nb) ? bsum[t] : 0;
    s[t] = v;
    __syncthreads();
    for (int o = 1; o < 512; o <<= 1) {
        int x = (t >= o) ? s[t - o] : 0;
        __syncthreads();
        s[t] += x;
        __syncthreads();
    }
    if (t < nb) boff[t] = s[t] - v;
}

__global__ void scan_add(int* __restrict__ rowstart, const int* __restrict__ boff,
                         int N, int E) {
    int i = blockIdx.x * blockDim.x + threadIdx.x;
    if (i < N) rowstart[i] += boff[i >> 8];
    if (i == 0) rowstart[N] = E;
}

__global__ void scatter_kernel(const int* __restrict__ ei, int E,
                               const int* __restrict__ rowstart,
                               const int* __restrict__ pos,
                               int* __restrict__ esrc) {
    int e = blockIdx.x * blockDim.x + threadIdx.x;
    if (e < E) {
        int d = ei[e];          // dst
        int s = ei[E + e];      // src
        esrc[rowstart[d] + pos[e]] = s;
    }
}

// ---------------- f32 -> bf16 convert (4 elements/thread) ----------------
__global__ void cvt_kernel(const float* __restrict__ x,
                           unsigned short* __restrict__ xb, long n) {
    long i = ((long)blockIdx.x * blockDim.x + threadIdx.x) * 4;
    if (i < n) {
        float4 v = *(const float4*)(x + i);
        ushort4 o;
        o.x = f32_to_bf16(v.x);
        o.y = f32_to_bf16(v.y);
        o.z = f32_to_bf16(v.z);
        o.w = f32_to_bf16(v.w);
        *(ushort4*)(xb + i) = o;
    }
}

// ---------------- fused conv ----------------
// agg = norm_i * ( norm_i*h_i + sum_j norm_j*hb_j )
// LAYER 0: self term from f32 x, gather from bf16 xb; epilogue: +x residual,
//          LayerNorm, write bf16.
// LAYER 1: self term from bf16 hb; epilogue: +x, write f32 out.
template <int LAYER>
__global__ __launch_bounds__(128) void conv_fused(const float* __restrict__ x,
                                                  const unsigned short* __restrict__ hb,
                                                  float* __restrict__ out,
                                                  unsigned short* __restrict__ outb,
                                                  const float* __restrict__ norm,
                                                  const int* __restrict__ rowstart,
                                                  const int* __restrict__ esrc) {
    __shared__ int nbr[128];
    __shared__ float nrm[128];
    __shared__ float red[2];
    int i = blockIdx.x;
    int t = threadIdx.x;
    int r0 = rowstart[i], r1 = rowstart[i + 1];
    float ni = norm[i];
    long base = (long)i * D_FEAT;

    float xval = x[base + t];               // f32 residual value (row-sequential)
    float acc;
    if (LAYER == 0) {
        acc = ni * xval;                    // self term from full-precision x
    } else {
        acc = ni * bf16_to_f32(hb[base + t]);
    }

    for (int b0 = r0; b0 < r1; b0 += 128) {
        int k = b0 + t;
        if (k < r1) {
            int j = esrc[k];
            nbr[t] = j;
            nrm[t] = norm[j];
        }
        __syncthreads();
        int cnt = min(128, r1 - b0);
        for (int q = 0; q < cnt; q++) {
            acc += nrm[q] * bf16_to_f32(hb[(long)nbr[q] * D_FEAT + t]);
        }
        __syncthreads();
    }

    float o = ni * acc;
    if (LAYER == 0) {
        o += xval;                          // residual
        // affine-free LayerNorm across the 128-thread row (2 waves)
        float s = o;
        #pragma unroll
        for (int m = 1; m < 64; m <<= 1) s += __shfl_xor(s, m);
        if ((t & 63) == 0) red[t >> 6] = s;
        __syncthreads();
        float mean = (red[0] + red[1]) * (1.0f / 128.0f);
        float d = o - mean;
        float vs = d * d;
        #pragma unroll
        for (int m = 1; m < 64; m <<= 1) vs += __shfl_xor(vs, m);
        __syncthreads();                    // red reuse
        if ((t & 63) == 0) red[t >> 6] = vs;
        __syncthreads();
        float rs = rsqrtf((red[0] + red[1]) * (1.0f / 128.0f) + 1e-5f);
        outb[base + t] = f32_to_bf16(d * rs);
    } else {
        out[base + t] = o + xval;           // final + ori
    }
}

// ---------------- launch ----------------

extern "C" void kernel_launch(void* const* d_in, const int* in_sizes, int n_in,
                              void* d_out, int out_size, void* d_ws, size_t ws_size,
                              hipStream_t stream) {
    const float* x = (const float*)d_in[0];
    const int* ei = (const int*)d_in[1];
    int N = in_sizes[0] / D_FEAT;
    int E = in_sizes[1] / 2;
    float* out = (float*)d_out;

    char* ws = (char*)d_ws;
    size_t off = 0;
    auto alloc = [&](size_t bytes) -> void* {
        size_t cur = (off + 511) & ~(size_t)511;
        off = cur + bytes;
        return (void*)(ws + cur);
    };
    int* deg             = (int*)alloc((size_t)N * 4);
    int* rowstart        = (int*)alloc((size_t)(N + 1) * 4);
    int* pos             = (int*)alloc((size_t)E * 4);
    int* esrc            = (int*)alloc((size_t)E * 4);
    float* norm          = (float*)alloc((size_t)N * 4);
    unsigned short* xb16 = (unsigned short*)alloc((size_t)N * D_FEAT * 2);
    unsigned short* h2b  = (unsigned short*)alloc((size_t)N * D_FEAT * 2);
    int* bsum            = (int*)alloc(1024 * 4);
    int* boff            = (int*)alloc(1024 * 4);
    (void)ws_size; (void)n_in; (void)out_size;

    (void)hipMemsetAsync(deg, 0, (size_t)N * 4, stream);

    int eb = (E + 255) / 256;
    hist_kernel<<<eb, 256, 0, stream>>>(ei, E, deg, pos);

    int nb = (N + 255) / 256;                 // 391 for N=100000, <=512
    scan_block<<<nb, 256, 0, stream>>>(deg, N, rowstart, bsum, norm);
    scan_top<<<1, 512, 0, stream>>>(bsum, boff, nb);
    scan_add<<<nb, 256, 0, stream>>>(rowstart, boff, N, E);
    scatter_kernel<<<eb, 256, 0, stream>>>(ei, E, rowstart, pos, esrc);

    long n = (long)N * D_FEAT;
    cvt_kernel<<<(int)((n / 4 + 255) / 256), 256, 0, stream>>>(x, xb16, n);

    // layer 0: h2b = bf16( LN( conv(x) + x ) )
    conv_fused<0><<<N, 128, 0, stream>>>(x, xb16, nullptr, h2b, norm, rowstart, esrc);
    // layer 1: out = conv(h2b) + x
    conv_fused<1><<<N, 128, 0, stream>>>(x, h2b, out, nullptr, norm, rowstart, esrc);
}